// Round 1
// baseline (728.136 us; speedup 1.0000x reference)
//
#include <hip/hip_runtime.h>

#define HW 3136          // 56*56
#define NPIX 25088       // 8*3136
#define NBLK 392         // NPIX/64

// workspace float offsets
#define OFF_Y1   0u
#define OFF_TR   1605632u
#define OFF_KERN 2007040u
#define OFF_OUT2 6924288u
#define OFF_Y3   8529920u
#define OFF_ST   14952448u
// stats sub-offsets (floats, relative to st base). acc: [C]=sum, [C..2C)=sumsq
#define ACC1 0
#define ACCR 128
#define ACC2 160
#define ACC3 288
#define FIN1 800
#define FINR 928
#define FIN2 960
#define FIN3 1088
// total stats floats used: 1600 (zero 2048)

__device__ __forceinline__ float wave_sum(float v) {
    #pragma unroll
    for (int off = 32; off > 0; off >>= 1) v += __shfl_xor(v, off, 64);
    return v;
}

// ---- K1: conv1x1 256->64 + stats -------------------------------------------
__global__ __launch_bounds__(256) void k_conv1(const float* __restrict__ x,
        const float* __restrict__ w1, float* __restrict__ y1, float* __restrict__ st) {
    __shared__ float xs[64][64];
    __shared__ float wsh[64][64];
    int t = threadIdx.x, pb = blockIdx.x;
    int b = pb / 49, hw0 = (pb % 49) * 64;
    int pix = t & 63, role = t >> 6;
    float acc[16];
    #pragma unroll
    for (int i = 0; i < 16; i++) acc[i] = 0.f;
    for (int cc = 0; cc < 4; cc++) {
        #pragma unroll
        for (int i = 0; i < 16; i++) {
            int e = i * 256 + t;
            int c = e >> 6, p = e & 63;
            xs[c][p]  = x[((b * 256) + cc * 64 + c) * HW + hw0 + p];
            wsh[c][p] = w1[c * 256 + cc * 64 + p];   // c=oc, p=ic within chunk
        }
        __syncthreads();
        #pragma unroll
        for (int i = 0; i < 16; i++) {
            int oc = role + 4 * i;
            float a = 0.f;
            #pragma unroll
            for (int c = 0; c < 64; c++) a += xs[c][pix] * wsh[oc][c];
            acc[i] += a;
        }
        __syncthreads();
    }
    #pragma unroll
    for (int i = 0; i < 16; i++) {
        int oc = role + 4 * i;
        float v = acc[i];
        y1[((b * 64) + oc) * HW + hw0 + pix] = v;
        float s  = wave_sum(v);
        float s2 = wave_sum(v * v);
        if (pix == 0) {
            atomicAdd(&st[ACC1 + oc], s);
            atomicAdd(&st[ACC1 + 64 + oc], s2);
        }
    }
}

// ---- finalize BN stats -> per-channel affine (a,b) -------------------------
__global__ void k_fin(const float* __restrict__ acc, float* __restrict__ fin,
                      const float* __restrict__ gamma, const float* __restrict__ beta, int C) {
    int c = threadIdx.x;
    if (c < C) {
        float mean = acc[c] * (1.0f / (float)NPIX);
        float var  = acc[C + c] * (1.0f / (float)NPIX) - mean * mean;
        float rstd = rsqrtf(var + 1e-5f);
        float a = gamma[c] * rstd;
        fin[c] = a;
        fin[C + c] = beta[c] - mean * a;
    }
}

// ---- K3: apply BN1+ReLU in-place, conv 64->16 + stats ----------------------
__global__ __launch_bounds__(256) void k_bn1_convr(float* __restrict__ y1,
        const float* __restrict__ wr, float* __restrict__ tr, float* __restrict__ st) {
    __shared__ float ys[64][64];
    __shared__ float wsh[16][64];
    int t = threadIdx.x, pb = blockIdx.x;
    int b = pb / 49, hw0 = (pb % 49) * 64;
    int pix = t & 63, role = t >> 6;
    #pragma unroll
    for (int i = 0; i < 16; i++) {
        int e = i * 256 + t;
        int c = e >> 6, p = e & 63;
        int gi = ((b * 64) + c) * HW + hw0 + p;
        float v = y1[gi];
        v = fmaxf(st[FIN1 + c] * v + st[FIN1 + 64 + c], 0.f);
        ys[c][p] = v;
        y1[gi] = v;                 // y1 becomes y1r
    }
    #pragma unroll
    for (int i = 0; i < 4; i++) {
        int ee = i * 256 + t;
        wsh[ee >> 6][ee & 63] = wr[ee];
    }
    __syncthreads();
    #pragma unroll
    for (int i = 0; i < 4; i++) {
        int oc = role + 4 * i;
        float a = 0.f;
        #pragma unroll
        for (int c = 0; c < 64; c++) a += wsh[oc][c] * ys[c][pix];
        tr[((b * 16) + oc) * HW + hw0 + pix] = a;
        float s  = wave_sum(a);
        float s2 = wave_sum(a * a);
        if (pix == 0) {
            atomicAdd(&st[ACCR + oc], s);
            atomicAdd(&st[ACCR + 16 + oc], s2);
        }
    }
}

// ---- K5: apply BNr+ReLU, conv 16->196 (per-pixel kernels) ------------------
__global__ __launch_bounds__(256) void k_bnr_convs(const float* __restrict__ tr,
        const float* __restrict__ wsp, float* __restrict__ kern, const float* __restrict__ st) {
    __shared__ float ts[16][64];
    __shared__ float wsh[196 * 16];
    int t = threadIdx.x, pb = blockIdx.x;
    int b = pb / 49, hw0 = (pb % 49) * 64;
    int pix = t & 63, role = t >> 6;
    #pragma unroll
    for (int i = 0; i < 4; i++) {
        int e = i * 256 + t;
        int c = e >> 6, p = e & 63;
        float v = tr[((b * 16) + c) * HW + hw0 + p];
        ts[c][p] = fmaxf(st[FINR + c] * v + st[FINR + 16 + c], 0.f);
    }
    for (int e = t; e < 3136; e += 256) wsh[e] = wsp[e];
    __syncthreads();
    for (int i = 0; i < 49; i++) {
        int oc = role + 4 * i;
        float a = 0.f;
        #pragma unroll
        for (int c = 0; c < 16; c++) a += wsh[oc * 16 + c] * ts[c][pix];
        kern[((b * 196) + oc) * HW + hw0 + pix] = a;
    }
}

// ---- K6: involution + stats ------------------------------------------------
__global__ __launch_bounds__(256) void k_invol(const float* __restrict__ y1r,
        const float* __restrict__ kern, float* __restrict__ out2, float* __restrict__ st) {
    __shared__ float ps[16][10][64];   // 16 ch, 4+6 rows halo, 56+6 cols (padded to 64)
    __shared__ float red[4][32];
    int t = threadIdx.x, bidx = blockIdx.x;     // ((b*4+g)*14 + ht)
    int ht = bidx % 14;
    int bg = bidx / 14;
    int g = bg & 3, b = bg >> 2;
    int h0 = ht * 4;
    for (int e = t; e < 16 * 10 * 64; e += 256) {
        int c = e / 640;
        int r = (e >> 6) % 10;
        int wc = e & 63;
        int gh = h0 + r - 3, gw = wc - 3;
        float v = 0.f;
        if (gh >= 0 && gh < 56 && gw >= 0 && gw < 56)
            v = y1r[((b * 64) + g * 16 + c) * HW + gh * 56 + gw];
        ps[c][r][wc] = v;
    }
    __syncthreads();
    float acc[16];
    #pragma unroll
    for (int c = 0; c < 16; c++) acc[c] = 0.f;
    bool active = t < 224;
    int lh = active ? (t / 56) : 0, lw = active ? (t % 56) : 0;
    if (active) {
        int hw = h0 * 56 + t;                  // contiguous over the tile
        const float* kp = kern + (size_t)(b * 196 + g * 49) * HW + hw;
        #pragma unroll 1
        for (int k = 0; k < 49; k++) {
            float kv = kp[(size_t)k * HW];
            int ki = k / 7, kj = k % 7;
            #pragma unroll
            for (int c = 0; c < 16; c++)
                acc[c] += kv * ps[c][lh + ki][lw + kj];
        }
        #pragma unroll
        for (int c = 0; c < 16; c++)
            out2[((b * 64) + g * 16 + c) * HW + hw] = acc[c];
    }
    int wave = t >> 6, lane = t & 63;
    #pragma unroll
    for (int c = 0; c < 16; c++) {
        float v = active ? acc[c] : 0.f;
        float s  = wave_sum(v);
        float s2 = wave_sum(v * v);
        if (lane == 0) { red[wave][c] = s; red[wave][16 + c] = s2; }
    }
    __syncthreads();
    if (t < 32) {
        float s = red[0][t] + red[1][t] + red[2][t] + red[3][t];
        int c = t & 15, isq = t >> 4;
        atomicAdd(&st[ACC2 + isq * 64 + g * 16 + c], s);
    }
}

// ---- K7: apply BN2+ReLU, conv 64->256 + stats ------------------------------
__global__ __launch_bounds__(256) void k_bn2_conv3(const float* __restrict__ out2,
        const float* __restrict__ w3, float* __restrict__ y3, float* __restrict__ st) {
    __shared__ float os[64][64];
    __shared__ float wsh[64][64];
    int t = threadIdx.x, pb = blockIdx.x;
    int b = pb / 49, hw0 = (pb % 49) * 64;
    int pix = t & 63, role = t >> 6;
    #pragma unroll
    for (int i = 0; i < 16; i++) {
        int e = i * 256 + t;
        int c = e >> 6, p = e & 63;
        float v = out2[((b * 64) + c) * HW + hw0 + p];
        os[c][p] = fmaxf(st[FIN2 + c] * v + st[FIN2 + 64 + c], 0.f);
    }
    __syncthreads();
    for (int occ = 0; occ < 4; occ++) {
        #pragma unroll
        for (int i = 0; i < 16; i++) {
            int e = i * 256 + t;
            int ocl = e >> 6, c = e & 63;
            wsh[ocl][c] = w3[(occ * 64 + ocl) * 64 + c];
        }
        __syncthreads();
        #pragma unroll
        for (int i = 0; i < 16; i++) {
            int ocl = role + 4 * i;
            int oc = occ * 64 + ocl;
            float a = 0.f;
            #pragma unroll
            for (int c = 0; c < 64; c++) a += wsh[ocl][c] * os[c][pix];
            y3[((b * 256) + oc) * HW + hw0 + pix] = a;
            float s  = wave_sum(a);
            float s2 = wave_sum(a * a);
            if (pix == 0) {
                atomicAdd(&st[ACC3 + oc], s);
                atomicAdd(&st[ACC3 + 256 + oc], s2);
            }
        }
        __syncthreads();
    }
}

// ---- K9: BN3 + residual + ReLU (float4) ------------------------------------
__global__ __launch_bounds__(256) void k_final(const float* __restrict__ y3,
        const float* __restrict__ x, float* __restrict__ out, const float* __restrict__ st) {
    int idx = blockIdx.x * 256 + threadIdx.x;   // float4 index
    if (idx < 1605632) {
        int c = (idx / 784) & 255;
        float a = st[FIN3 + c], bb = st[FIN3 + 256 + c];
        float4 v  = ((const float4*)y3)[idx];
        float4 xv = ((const float4*)x)[idx];
        float4 o;
        o.x = fmaxf(a * v.x + bb + xv.x, 0.f);
        o.y = fmaxf(a * v.y + bb + xv.y, 0.f);
        o.z = fmaxf(a * v.z + bb + xv.z, 0.f);
        o.w = fmaxf(a * v.w + bb + xv.w, 0.f);
        ((float4*)out)[idx] = o;
    }
}

extern "C" void kernel_launch(void* const* d_in, const int* in_sizes, int n_in,
                              void* d_out, int out_size, void* d_ws, size_t ws_size,
                              hipStream_t stream) {
    const float* x   = (const float*)d_in[0];
    const float* w1  = (const float*)d_in[1];
    const float* g1  = (const float*)d_in[2];
    const float* b1  = (const float*)d_in[3];
    const float* wr  = (const float*)d_in[4];
    const float* gr  = (const float*)d_in[5];
    const float* br  = (const float*)d_in[6];
    const float* wsp = (const float*)d_in[7];
    const float* g2  = (const float*)d_in[8];
    const float* b2  = (const float*)d_in[9];
    const float* w3  = (const float*)d_in[10];
    const float* g3  = (const float*)d_in[11];
    const float* b3  = (const float*)d_in[12];
    float* out = (float*)d_out;
    float* w   = (float*)d_ws;
    float* y1   = w + OFF_Y1;
    float* tr   = w + OFF_TR;
    float* kern = w + OFF_KERN;
    float* out2 = w + OFF_OUT2;
    float* y3   = w + OFF_Y3;
    float* st   = w + OFF_ST;

    hipMemsetAsync(st, 0, 2048 * sizeof(float), stream);
    k_conv1<<<NBLK, 256, 0, stream>>>(x, w1, y1, st);
    k_fin<<<1, 64, 0, stream>>>(st + ACC1, st + FIN1, g1, b1, 64);
    k_bn1_convr<<<NBLK, 256, 0, stream>>>(y1, wr, tr, st);
    k_fin<<<1, 16, 0, stream>>>(st + ACCR, st + FINR, gr, br, 16);
    k_bnr_convs<<<NBLK, 256, 0, stream>>>(tr, wsp, kern, st);
    k_invol<<<448, 256, 0, stream>>>(y1, kern, out2, st);
    k_fin<<<1, 64, 0, stream>>>(st + ACC2, st + FIN2, g2, b2, 64);
    k_bn2_conv3<<<NBLK, 256, 0, stream>>>(out2, w3, y3, st);
    k_fin<<<1, 256, 0, stream>>>(st + ACC3, st + FIN3, g3, b3, 256);
    k_final<<<6272, 256, 0, stream>>>(y3, x, out, st);
}

// Round 3
// 428.334 us; speedup vs baseline: 1.6999x; 1.6999x over previous
//
#include <hip/hip_runtime.h>

#define HW 3136          // 56*56
#define NPIX 25088       // 8*3136
#define NBLK 392         // NPIX/64

// workspace float offsets
#define OFF_Y1   0u
#define OFF_TR   1605632u
#define OFF_WT   2007040u      // w1t (16384) + w3t (16384)
#define OFF_OUT2 6924288u
#define OFF_Y3   8529920u
#define OFF_ST   14952448u
// stats sub-offsets (floats, relative to st base). acc: [C]=sum, [C..2C)=sumsq
#define ACC1 0
#define ACCR 128
#define ACC2 160
#define ACC3 288
#define FIN1 800
#define FINR 928
#define FIN2 960
#define FIN3 1088

__device__ __forceinline__ float wave_sum(float v) {
    #pragma unroll
    for (int off = 32; off > 0; off >>= 1) v += __shfl_xor(v, off, 64);
    return v;
}

// ---- K0: transpose weights w1[64][256]->w1t[256][64], w3[256][64]->w3t[64][256]
__global__ __launch_bounds__(256) void k_wt(const float* __restrict__ w1,
        const float* __restrict__ w3, float* __restrict__ w1t, float* __restrict__ w3t) {
    int i = blockIdx.x * 256 + threadIdx.x;
    if (i < 16384) {
        int oc = i >> 8, ic = i & 255;
        w1t[ic * 64 + oc] = w1[i];
    } else {
        int j = i - 16384;
        int oc = j >> 6, ic = j & 63;
        w3t[ic * 256 + oc] = w3[j];
    }
}

// ---- K1: conv1x1 256->64 + stats, 4x4 register tile ------------------------
__global__ __launch_bounds__(256) void k_conv1(const float* __restrict__ x,
        const float* __restrict__ w1t, float* __restrict__ y1, float* __restrict__ st) {
    __shared__ float xs[64][64];    // [ic][pix]
    __shared__ float wst[64][64];   // [ic][oc]
    int t = threadIdx.x, pb = blockIdx.x;
    int b = pb / 49, hw0 = (pb % 49) * 64;
    int tx = t & 15, ty = t >> 4;     // pix group / oc group
    float acc[4][4];
    #pragma unroll
    for (int i = 0; i < 4; i++)
        #pragma unroll
        for (int j = 0; j < 4; j++) acc[i][j] = 0.f;
    for (int cc = 0; cc < 4; cc++) {
        #pragma unroll
        for (int i = 0; i < 16; i++) {
            int e = i * 256 + t, c = e >> 6, p = e & 63;
            xs[c][p]  = x[((b * 256) + cc * 64 + c) * HW + hw0 + p];
            wst[c][p] = w1t[(cc * 64 + c) * 64 + p];
        }
        __syncthreads();
        #pragma unroll
        for (int c = 0; c < 64; c++) {
            float4 xv = *(const float4*)&xs[c][tx * 4];
            float4 wv = *(const float4*)&wst[c][ty * 4];
            float xa[4] = {xv.x, xv.y, xv.z, xv.w};
            float wa[4] = {wv.x, wv.y, wv.z, wv.w};
            #pragma unroll
            for (int i = 0; i < 4; i++)
                #pragma unroll
                for (int j = 0; j < 4; j++) acc[i][j] = fmaf(wa[i], xa[j], acc[i][j]);
        }
        __syncthreads();
    }
    #pragma unroll
    for (int i = 0; i < 4; i++) {
        int oc = ty * 4 + i;
        float4 o = make_float4(acc[i][0], acc[i][1], acc[i][2], acc[i][3]);
        *(float4*)&y1[((b * 64) + oc) * HW + hw0 + tx * 4] = o;
        float s = o.x + o.y + o.z + o.w;
        float q = o.x * o.x + o.y * o.y + o.z * o.z + o.w * o.w;
        #pragma unroll
        for (int off = 1; off <= 8; off <<= 1) {
            s += __shfl_xor(s, off, 64);
            q += __shfl_xor(q, off, 64);
        }
        if (tx == 0) {
            atomicAdd(&st[ACC1 + oc], s);
            atomicAdd(&st[ACC1 + 64 + oc], q);
        }
    }
}

// ---- finalize BN stats -> per-channel affine (a,b) -------------------------
__global__ void k_fin(const float* __restrict__ acc, float* __restrict__ fin,
                      const float* __restrict__ gamma, const float* __restrict__ beta, int C) {
    int c = threadIdx.x;
    if (c < C) {
        float mean = acc[c] * (1.0f / (float)NPIX);
        float var  = acc[C + c] * (1.0f / (float)NPIX) - mean * mean;
        float rstd = rsqrtf(var + 1e-5f);
        float a = gamma[c] * rstd;
        fin[c] = a;
        fin[C + c] = beta[c] - mean * a;
    }
}

// ---- K3: apply BN1+ReLU in-place, conv 64->16 + stats ----------------------
__global__ __launch_bounds__(256) void k_bn1_convr(float* __restrict__ y1,
        const float* __restrict__ wr, float* __restrict__ tr, float* __restrict__ st) {
    __shared__ float ys[64][64];    // [ic][pix], BN1+ReLU applied
    __shared__ float wsh[16][64];   // [oc][ic]
    int t = threadIdx.x, pb = blockIdx.x;
    int b = pb / 49, hw0 = (pb % 49) * 64;
    int tx = t & 15, ty = t >> 4;   // pix group (4 pix) / oc (one of 16)
    #pragma unroll
    for (int i = 0; i < 16; i++) {
        int e = i * 256 + t, c = e >> 6, p = e & 63;
        int gi = ((b * 64) + c) * HW + hw0 + p;
        float v = y1[gi];
        v = fmaxf(st[FIN1 + c] * v + st[FIN1 + 64 + c], 0.f);
        ys[c][p] = v;
        y1[gi] = v;                 // y1 becomes y1r
    }
    #pragma unroll
    for (int i = 0; i < 4; i++) {
        int e = i * 256 + t;
        wsh[e >> 6][e & 63] = wr[e];
    }
    __syncthreads();
    float a0 = 0.f, a1 = 0.f, a2 = 0.f, a3 = 0.f;
    #pragma unroll
    for (int c = 0; c < 64; c++) {
        float4 yv = *(const float4*)&ys[c][tx * 4];
        float wv = wsh[ty][c];
        a0 = fmaf(wv, yv.x, a0); a1 = fmaf(wv, yv.y, a1);
        a2 = fmaf(wv, yv.z, a2); a3 = fmaf(wv, yv.w, a3);
    }
    *(float4*)&tr[((b * 16) + ty) * HW + hw0 + tx * 4] = make_float4(a0, a1, a2, a3);
    float s = a0 + a1 + a2 + a3;
    float q = a0 * a0 + a1 * a1 + a2 * a2 + a3 * a3;
    #pragma unroll
    for (int off = 1; off <= 8; off <<= 1) {
        s += __shfl_xor(s, off, 64);
        q += __shfl_xor(q, off, 64);
    }
    if (tx == 0) {
        atomicAdd(&st[ACCR + ty], s);
        atomicAdd(&st[ACCR + 16 + ty], q);
    }
}

// ---- K6: fused BNr+ReLU -> span conv (kernels in regs) -> involution + stats
__global__ __launch_bounds__(256) void k_invol(const float* __restrict__ y1r,
        const float* __restrict__ tr, const float* __restrict__ wsp,
        float* __restrict__ out2, float* __restrict__ st) {
    __shared__ float ts[16][256];      // BNr+ReLU'd tr tile (224 used)
    __shared__ float sw[49][16];       // span weights for this group
    __shared__ float ps[16][10][64];   // y1r halo tile
    __shared__ float red[4][32];
    int t = threadIdx.x, bidx = blockIdx.x;     // ((b*4+g)*14 + ht)
    int ht = bidx % 14;
    int bg = bidx / 14;
    int g = bg & 3, b = bg >> 2;
    int h0 = ht * 4;
    // stage ts (BNr+ReLU applied)
    #pragma unroll
    for (int i = 0; i < 16; i++) {
        int e = i * 256 + t, c = e >> 8, p = e & 255;
        if (p < 224) {
            float v = tr[((b * 16) + c) * HW + h0 * 56 + p];
            ts[c][p] = fmaxf(st[FINR + c] * v + st[FINR + 16 + c], 0.f);
        }
    }
    // stage span weights (group g): contiguous 784 floats
    for (int e = t; e < 784; e += 256) sw[e >> 4][e & 15] = wsp[g * 784 + e];
    // stage y1r halo
    for (int e = t; e < 10240; e += 256) {
        int c = e / 640, r = (e >> 6) % 10, wc = e & 63;
        int gh = h0 + r - 3, gw = wc - 3;
        float v = 0.f;
        if (gh >= 0 && gh < 56 && gw >= 0 && gw < 56)
            v = y1r[((b * 64) + g * 16 + c) * HW + gh * 56 + gw];
        ps[c][r][wc] = v;
    }
    __syncthreads();
    float accv[16];
    #pragma unroll
    for (int c = 0; c < 16; c++) accv[c] = 0.f;
    bool active = t < 224;
    if (active) {
        int lh = t / 56, lw = t % 56;
        // per-pixel kernel generation into registers
        float tsr[16];
        #pragma unroll
        for (int c = 0; c < 16; c++) tsr[c] = ts[c][t];
        float kr[49];
        #pragma unroll
        for (int k = 0; k < 49; k++) {
            const float4* swr = (const float4*)&sw[k][0];
            float4 u0 = swr[0], u1 = swr[1], u2 = swr[2], u3 = swr[3];
            float v = u0.x * tsr[0];
            v = fmaf(u0.y, tsr[1], v);  v = fmaf(u0.z, tsr[2], v);  v = fmaf(u0.w, tsr[3], v);
            v = fmaf(u1.x, tsr[4], v);  v = fmaf(u1.y, tsr[5], v);  v = fmaf(u1.z, tsr[6], v);
            v = fmaf(u1.w, tsr[7], v);  v = fmaf(u2.x, tsr[8], v);  v = fmaf(u2.y, tsr[9], v);
            v = fmaf(u2.z, tsr[10], v); v = fmaf(u2.w, tsr[11], v); v = fmaf(u3.x, tsr[12], v);
            v = fmaf(u3.y, tsr[13], v); v = fmaf(u3.z, tsr[14], v); v = fmaf(u3.w, tsr[15], v);
            kr[k] = v;
        }
        // involution MAC
        #pragma unroll
        for (int k = 0; k < 49; k++) {
            int ki = k / 7, kj = k % 7;
            float kv = kr[k];
            #pragma unroll
            for (int c = 0; c < 16; c++)
                accv[c] = fmaf(kv, ps[c][lh + ki][lw + kj], accv[c]);
        }
        int hw = h0 * 56 + t;
        #pragma unroll
        for (int c = 0; c < 16; c++)
            out2[((b * 64) + g * 16 + c) * HW + hw] = accv[c];
    }
    int wave = t >> 6, lane = t & 63;
    #pragma unroll
    for (int c = 0; c < 16; c++) {
        float v = active ? accv[c] : 0.f;
        float s  = wave_sum(v);
        float s2 = wave_sum(v * v);
        if (lane == 0) { red[wave][c] = s; red[wave][16 + c] = s2; }
    }
    __syncthreads();
    if (t < 32) {
        float s = red[0][t] + red[1][t] + red[2][t] + red[3][t];
        atomicAdd(&st[ACC2 + (t >> 4) * 64 + g * 16 + (t & 15)], s);
    }
}

// ---- K7: apply BN2+ReLU, conv 64->256 + stats, 4x4 register tile -----------
__global__ __launch_bounds__(256) void k_bn2_conv3(const float* __restrict__ out2,
        const float* __restrict__ w3t, float* __restrict__ y3, float* __restrict__ st) {
    __shared__ float os[64][64];    // [ic][pix], BN2+ReLU applied
    __shared__ float wst[64][64];   // [ic][oc-chunk]
    int t = threadIdx.x, pb = blockIdx.x;
    int b = pb / 49, hw0 = (pb % 49) * 64;
    int tx = t & 15, ty = t >> 4;
    #pragma unroll
    for (int i = 0; i < 16; i++) {
        int e = i * 256 + t, c = e >> 6, p = e & 63;
        float v = out2[((b * 64) + c) * HW + hw0 + p];
        os[c][p] = fmaxf(st[FIN2 + c] * v + st[FIN2 + 64 + c], 0.f);
    }
    for (int occ = 0; occ < 4; occ++) {
        #pragma unroll
        for (int i = 0; i < 16; i++) {
            int e = i * 256 + t, c = e >> 6, p = e & 63;
            wst[c][p] = w3t[c * 256 + occ * 64 + p];
        }
        __syncthreads();
        float acc[4][4];
        #pragma unroll
        for (int i = 0; i < 4; i++)
            #pragma unroll
            for (int j = 0; j < 4; j++) acc[i][j] = 0.f;
        #pragma unroll
        for (int c = 0; c < 64; c++) {
            float4 xv = *(const float4*)&os[c][tx * 4];
            float4 wv = *(const float4*)&wst[c][ty * 4];
            float xa[4] = {xv.x, xv.y, xv.z, xv.w};
            float wa[4] = {wv.x, wv.y, wv.z, wv.w};
            #pragma unroll
            for (int i = 0; i < 4; i++)
                #pragma unroll
                for (int j = 0; j < 4; j++) acc[i][j] = fmaf(wa[i], xa[j], acc[i][j]);
        }
        #pragma unroll
        for (int i = 0; i < 4; i++) {
            int oc = occ * 64 + ty * 4 + i;
            float4 o = make_float4(acc[i][0], acc[i][1], acc[i][2], acc[i][3]);
            *(float4*)&y3[((b * 256) + oc) * HW + hw0 + tx * 4] = o;
            float s = o.x + o.y + o.z + o.w;
            float q = o.x * o.x + o.y * o.y + o.z * o.z + o.w * o.w;
            #pragma unroll
            for (int off = 1; off <= 8; off <<= 1) {
                s += __shfl_xor(s, off, 64);
                q += __shfl_xor(q, off, 64);
            }
            if (tx == 0) {
                atomicAdd(&st[ACC3 + oc], s);
                atomicAdd(&st[ACC3 + 256 + oc], q);
            }
        }
        __syncthreads();
    }
}

// ---- K9: BN3 + residual + ReLU (float4) ------------------------------------
__global__ __launch_bounds__(256) void k_final(const float* __restrict__ y3,
        const float* __restrict__ x, float* __restrict__ out, const float* __restrict__ st) {
    int idx = blockIdx.x * 256 + threadIdx.x;   // float4 index
    if (idx < 1605632) {
        int c = (idx / 784) & 255;
        float a = st[FIN3 + c], bb = st[FIN3 + 256 + c];
        float4 v  = ((const float4*)y3)[idx];
        float4 xv = ((const float4*)x)[idx];
        float4 o;
        o.x = fmaxf(a * v.x + bb + xv.x, 0.f);
        o.y = fmaxf(a * v.y + bb + xv.y, 0.f);
        o.z = fmaxf(a * v.z + bb + xv.z, 0.f);
        o.w = fmaxf(a * v.w + bb + xv.w, 0.f);
        ((float4*)out)[idx] = o;
    }
}

extern "C" void kernel_launch(void* const* d_in, const int* in_sizes, int n_in,
                              void* d_out, int out_size, void* d_ws, size_t ws_size,
                              hipStream_t stream) {
    const float* x   = (const float*)d_in[0];
    const float* w1  = (const float*)d_in[1];
    const float* g1  = (const float*)d_in[2];
    const float* b1  = (const float*)d_in[3];
    const float* wr  = (const float*)d_in[4];
    const float* gr  = (const float*)d_in[5];
    const float* br  = (const float*)d_in[6];
    const float* wsp = (const float*)d_in[7];
    const float* g2  = (const float*)d_in[8];
    const float* b2  = (const float*)d_in[9];
    const float* w3  = (const float*)d_in[10];
    const float* g3  = (const float*)d_in[11];
    const float* b3  = (const float*)d_in[12];
    float* out = (float*)d_out;
    float* w   = (float*)d_ws;
    float* y1   = w + OFF_Y1;
    float* tr   = w + OFF_TR;
    float* w1t  = w + OFF_WT;
    float* w3t  = w + OFF_WT + 16384;
    float* out2 = w + OFF_OUT2;
    float* y3   = w + OFF_Y3;
    float* st   = w + OFF_ST;

    hipMemsetAsync(st, 0, 2048 * sizeof(float), stream);
    k_wt<<<128, 256, 0, stream>>>(w1, w3, w1t, w3t);
    k_conv1<<<NBLK, 256, 0, stream>>>(x, w1t, y1, st);
    k_fin<<<1, 64, 0, stream>>>(st + ACC1, st + FIN1, g1, b1, 64);
    k_bn1_convr<<<NBLK, 256, 0, stream>>>(y1, wr, tr, st);
    k_fin<<<1, 64, 0, stream>>>(st + ACCR, st + FINR, gr, br, 16);
    k_invol<<<448, 256, 0, stream>>>(y1, tr, wsp, out2, st);
    k_fin<<<1, 64, 0, stream>>>(st + ACC2, st + FIN2, g2, b2, 64);
    k_bn2_conv3<<<NBLK, 256, 0, stream>>>(out2, w3t, y3, st);
    k_fin<<<1, 256, 0, stream>>>(st + ACC3, st + FIN3, g3, b3, 256);
    k_final<<<6272, 256, 0, stream>>>(y3, x, out, st);
}

// Round 5
// 296.028 us; speedup vs baseline: 2.4597x; 1.4469x over previous
//
#include <hip/hip_runtime.h>

#define HW 3136          // 56*56
#define NPIX 25088       // 8*3136
#define NBLK 392         // NPIX/64

// workspace float offsets
#define OFF_Y1   0u
#define OFF_TR   1605632u
#define OFF_WT   2007040u      // w1t (16384) + w3t (16384)
#define OFF_OUT2 6924288u
#define OFF_Y3   8529920u
#define OFF_ST   14952448u
// stats sub-offsets (floats, relative to st base). acc: [C]=sum, [C..2C)=sumsq
#define ACC1 0
#define ACCR 128
#define ACC2 160
#define ACC3 288
#define FIN1 800
#define FINR 928
#define FIN2 960
#define FIN3 1088

__device__ __forceinline__ float wave_sum(float v) {
    #pragma unroll
    for (int off = 32; off > 0; off >>= 1) v += __shfl_xor(v, off, 64);
    return v;
}

// ---- K0: transpose weights w1[64][256]->w1t[256][64], w3[256][64]->w3t[64][256]
__global__ __launch_bounds__(256) void k_wt(const float* __restrict__ w1,
        const float* __restrict__ w3, float* __restrict__ w1t, float* __restrict__ w3t) {
    int i = blockIdx.x * 256 + threadIdx.x;
    if (i < 16384) {
        int oc = i >> 8, ic = i & 255;
        w1t[ic * 64 + oc] = w1[i];
    } else {
        int j = i - 16384;
        int oc = j >> 6, ic = j & 63;
        w3t[ic * 256 + oc] = w3[j];
    }
}

// ---- K1: conv1x1 256->64 + stats, 4x4 register tile ------------------------
// cc loop pinned (reduction); VGPR capped at 128 via launch_bounds min-waves=4.
__global__ __launch_bounds__(256, 4) void k_conv1(const float* __restrict__ x,
        const float* __restrict__ w1t, float* __restrict__ y1, float* __restrict__ st) {
    __shared__ float xs[64][64];    // [ic][pix]
    __shared__ float wst[64][64];   // [ic][oc]
    int t = threadIdx.x, pb = blockIdx.x;
    int b = pb / 49, hw0 = (pb % 49) * 64;
    int tx = t & 15, ty = t >> 4;     // pix group / oc group
    float acc[4][4];
    #pragma unroll
    for (int i = 0; i < 4; i++)
        #pragma unroll
        for (int j = 0; j < 4; j++) acc[i][j] = 0.f;
    #pragma unroll 1
    for (int cc = 0; cc < 4; cc++) {
        #pragma unroll
        for (int i = 0; i < 16; i++) {
            int e = i * 256 + t, c = e >> 6, p = e & 63;
            xs[c][p]  = x[((b * 256) + cc * 64 + c) * HW + hw0 + p];
            wst[c][p] = w1t[(cc * 64 + c) * 64 + p];
        }
        __syncthreads();
        #pragma unroll 8
        for (int c = 0; c < 64; c++) {
            float4 xv = *(const float4*)&xs[c][tx * 4];
            float4 wv = *(const float4*)&wst[c][ty * 4];
            float xa[4] = {xv.x, xv.y, xv.z, xv.w};
            float wa[4] = {wv.x, wv.y, wv.z, wv.w};
            #pragma unroll
            for (int i = 0; i < 4; i++)
                #pragma unroll
                for (int j = 0; j < 4; j++) acc[i][j] = fmaf(wa[i], xa[j], acc[i][j]);
        }
        __syncthreads();
    }
    #pragma unroll
    for (int i = 0; i < 4; i++) {
        int oc = ty * 4 + i;
        float4 o = make_float4(acc[i][0], acc[i][1], acc[i][2], acc[i][3]);
        *(float4*)&y1[((b * 64) + oc) * HW + hw0 + tx * 4] = o;
        float s = o.x + o.y + o.z + o.w;
        float q = o.x * o.x + o.y * o.y + o.z * o.z + o.w * o.w;
        #pragma unroll
        for (int off = 1; off <= 8; off <<= 1) {
            s += __shfl_xor(s, off, 64);
            q += __shfl_xor(q, off, 64);
        }
        if (tx == 0) {
            atomicAdd(&st[ACC1 + oc], s);
            atomicAdd(&st[ACC1 + 64 + oc], q);
        }
    }
}

// ---- finalize BN stats -> per-channel affine (a,b) -------------------------
__global__ void k_fin(const float* __restrict__ acc, float* __restrict__ fin,
                      const float* __restrict__ gamma, const float* __restrict__ beta, int C) {
    int c = threadIdx.x;
    if (c < C) {
        float mean = acc[c] * (1.0f / (float)NPIX);
        float var  = acc[C + c] * (1.0f / (float)NPIX) - mean * mean;
        float rstd = rsqrtf(var + 1e-5f);
        float a = gamma[c] * rstd;
        fin[c] = a;
        fin[C + c] = beta[c] - mean * a;
    }
}

// ---- K3: apply BN1+ReLU in-place, conv 64->16 + stats ----------------------
__global__ __launch_bounds__(256, 4) void k_bn1_convr(float* __restrict__ y1,
        const float* __restrict__ wr, float* __restrict__ tr, float* __restrict__ st) {
    __shared__ float ys[64][64];    // [ic][pix], BN1+ReLU applied
    __shared__ float wsh[16][64];   // [oc][ic]
    int t = threadIdx.x, pb = blockIdx.x;
    int b = pb / 49, hw0 = (pb % 49) * 64;
    int tx = t & 15, ty = t >> 4;   // pix group (4 pix) / oc (one of 16)
    #pragma unroll
    for (int i = 0; i < 16; i++) {
        int e = i * 256 + t, c = e >> 6, p = e & 63;
        int gi = ((b * 64) + c) * HW + hw0 + p;
        float v = y1[gi];
        v = fmaxf(st[FIN1 + c] * v + st[FIN1 + 64 + c], 0.f);
        ys[c][p] = v;
        y1[gi] = v;                 // y1 becomes y1r
    }
    #pragma unroll
    for (int i = 0; i < 4; i++) {
        int e = i * 256 + t;
        wsh[e >> 6][e & 63] = wr[e];
    }
    __syncthreads();
    float a0 = 0.f, a1 = 0.f, a2 = 0.f, a3 = 0.f;
    #pragma unroll 8
    for (int c = 0; c < 64; c++) {
        float4 yv = *(const float4*)&ys[c][tx * 4];
        float wv = wsh[ty][c];
        a0 = fmaf(wv, yv.x, a0); a1 = fmaf(wv, yv.y, a1);
        a2 = fmaf(wv, yv.z, a2); a3 = fmaf(wv, yv.w, a3);
    }
    *(float4*)&tr[((b * 16) + ty) * HW + hw0 + tx * 4] = make_float4(a0, a1, a2, a3);
    float s = a0 + a1 + a2 + a3;
    float q = a0 * a0 + a1 * a1 + a2 * a2 + a3 * a3;
    #pragma unroll
    for (int off = 1; off <= 8; off <<= 1) {
        s += __shfl_xor(s, off, 64);
        q += __shfl_xor(q, off, 64);
    }
    if (tx == 0) {
        atomicAdd(&st[ACCR + ty], s);
        atomicAdd(&st[ACCR + 16 + ty], q);
    }
}

// ---- K6: fused BNr+ReLU -> span conv (kernels in regs) -> involution + stats
__global__ __launch_bounds__(256) void k_invol(const float* __restrict__ y1r,
        const float* __restrict__ tr, const float* __restrict__ wsp,
        float* __restrict__ out2, float* __restrict__ st) {
    __shared__ float ts[16][256];      // BNr+ReLU'd tr tile (224 used)
    __shared__ float sw[49][16];       // span weights for this group
    __shared__ float ps[16][10][64];   // y1r halo tile
    __shared__ float red[4][32];
    int t = threadIdx.x, bidx = blockIdx.x;     // ((b*4+g)*14 + ht)
    int ht = bidx % 14;
    int bg = bidx / 14;
    int g = bg & 3, b = bg >> 2;
    int h0 = ht * 4;
    // stage ts (BNr+ReLU applied)
    #pragma unroll
    for (int i = 0; i < 16; i++) {
        int e = i * 256 + t, c = e >> 8, p = e & 255;
        if (p < 224) {
            float v = tr[((b * 16) + c) * HW + h0 * 56 + p];
            ts[c][p] = fmaxf(st[FINR + c] * v + st[FINR + 16 + c], 0.f);
        }
    }
    // stage span weights (group g): contiguous 784 floats
    for (int e = t; e < 784; e += 256) sw[e >> 4][e & 15] = wsp[g * 784 + e];
    // stage y1r halo
    for (int e = t; e < 10240; e += 256) {
        int c = e / 640, r = (e >> 6) % 10, wc = e & 63;
        int gh = h0 + r - 3, gw = wc - 3;
        float v = 0.f;
        if (gh >= 0 && gh < 56 && gw >= 0 && gw < 56)
            v = y1r[((b * 64) + g * 16 + c) * HW + gh * 56 + gw];
        ps[c][r][wc] = v;
    }
    __syncthreads();
    float accv[16];
    #pragma unroll
    for (int c = 0; c < 16; c++) accv[c] = 0.f;
    bool active = t < 224;
    if (active) {
        int lh = t / 56, lw = t % 56;
        // per-pixel kernel generation into registers
        float tsr[16];
        #pragma unroll
        for (int c = 0; c < 16; c++) tsr[c] = ts[c][t];
        float kr[49];
        #pragma unroll
        for (int k = 0; k < 49; k++) {
            const float4* swr = (const float4*)&sw[k][0];
            float4 u0 = swr[0], u1 = swr[1], u2 = swr[2], u3 = swr[3];
            float v = u0.x * tsr[0];
            v = fmaf(u0.y, tsr[1], v);  v = fmaf(u0.z, tsr[2], v);  v = fmaf(u0.w, tsr[3], v);
            v = fmaf(u1.x, tsr[4], v);  v = fmaf(u1.y, tsr[5], v);  v = fmaf(u1.z, tsr[6], v);
            v = fmaf(u1.w, tsr[7], v);  v = fmaf(u2.x, tsr[8], v);  v = fmaf(u2.y, tsr[9], v);
            v = fmaf(u2.z, tsr[10], v); v = fmaf(u2.w, tsr[11], v); v = fmaf(u3.x, tsr[12], v);
            v = fmaf(u3.y, tsr[13], v); v = fmaf(u3.z, tsr[14], v); v = fmaf(u3.w, tsr[15], v);
            kr[k] = v;
        }
        // involution MAC
        #pragma unroll
        for (int k = 0; k < 49; k++) {
            int ki = k / 7, kj = k % 7;
            float kv = kr[k];
            #pragma unroll
            for (int c = 0; c < 16; c++)
                accv[c] = fmaf(kv, ps[c][lh + ki][lw + kj], accv[c]);
        }
        int hw = h0 * 56 + t;
        #pragma unroll
        for (int c = 0; c < 16; c++)
            out2[((b * 64) + g * 16 + c) * HW + hw] = accv[c];
    }
    int wave = t >> 6, lane = t & 63;
    #pragma unroll
    for (int c = 0; c < 16; c++) {
        float v = active ? accv[c] : 0.f;
        float s  = wave_sum(v);
        float s2 = wave_sum(v * v);
        if (lane == 0) { red[wave][c] = s; red[wave][16 + c] = s2; }
    }
    __syncthreads();
    if (t < 32) {
        float s = red[0][t] + red[1][t] + red[2][t] + red[3][t];
        atomicAdd(&st[ACC2 + (t >> 4) * 64 + g * 16 + (t & 15)], s);
    }
}

// ---- K7: apply BN2+ReLU, conv 64->256 + stats ------------------------------
// occ chunk moved to grid (blockIdx & 3): one staging + one inner loop per block.
__global__ __launch_bounds__(256, 4) void k_bn2_conv3(const float* __restrict__ out2,
        const float* __restrict__ w3t, float* __restrict__ y3, float* __restrict__ st) {
    __shared__ float os[64][64];    // [ic][pix], BN2+ReLU applied
    __shared__ float wst[64][64];   // [ic][oc-chunk]
    int t = threadIdx.x, blk = blockIdx.x;
    int occ = blk & 3, pb = blk >> 2;
    int b = pb / 49, hw0 = (pb % 49) * 64;
    int tx = t & 15, ty = t >> 4;
    #pragma unroll
    for (int i = 0; i < 16; i++) {
        int e = i * 256 + t, c = e >> 6, p = e & 63;
        float v = out2[((b * 64) + c) * HW + hw0 + p];
        os[c][p] = fmaxf(st[FIN2 + c] * v + st[FIN2 + 64 + c], 0.f);
        wst[c][p] = w3t[c * 256 + occ * 64 + p];
    }
    __syncthreads();
    float acc[4][4];
    #pragma unroll
    for (int i = 0; i < 4; i++)
        #pragma unroll
        for (int j = 0; j < 4; j++) acc[i][j] = 0.f;
    #pragma unroll 8
    for (int c = 0; c < 64; c++) {
        float4 xv = *(const float4*)&os[c][tx * 4];
        float4 wv = *(const float4*)&wst[c][ty * 4];
        float xa[4] = {xv.x, xv.y, xv.z, xv.w};
        float wa[4] = {wv.x, wv.y, wv.z, wv.w};
        #pragma unroll
        for (int i = 0; i < 4; i++)
            #pragma unroll
            for (int j = 0; j < 4; j++) acc[i][j] = fmaf(wa[i], xa[j], acc[i][j]);
    }
    #pragma unroll
    for (int i = 0; i < 4; i++) {
        int oc = occ * 64 + ty * 4 + i;
        float4 o = make_float4(acc[i][0], acc[i][1], acc[i][2], acc[i][3]);
        *(float4*)&y3[((b * 256) + oc) * HW + hw0 + tx * 4] = o;
        float s = o.x + o.y + o.z + o.w;
        float q = o.x * o.x + o.y * o.y + o.z * o.z + o.w * o.w;
        #pragma unroll
        for (int off = 1; off <= 8; off <<= 1) {
            s += __shfl_xor(s, off, 64);
            q += __shfl_xor(q, off, 64);
        }
        if (tx == 0) {
            atomicAdd(&st[ACC3 + oc], s);
            atomicAdd(&st[ACC3 + 256 + oc], q);
        }
    }
}

// ---- K9: BN3 + residual + ReLU (float4) ------------------------------------
__global__ __launch_bounds__(256) void k_final(const float* __restrict__ y3,
        const float* __restrict__ x, float* __restrict__ out, const float* __restrict__ st) {
    int idx = blockIdx.x * 256 + threadIdx.x;   // float4 index
    if (idx < 1605632) {
        int c = (idx / 784) & 255;
        float a = st[FIN3 + c], bb = st[FIN3 + 256 + c];
        float4 v  = ((const float4*)y3)[idx];
        float4 xv = ((const float4*)x)[idx];
        float4 o;
        o.x = fmaxf(a * v.x + bb + xv.x, 0.f);
        o.y = fmaxf(a * v.y + bb + xv.y, 0.f);
        o.z = fmaxf(a * v.z + bb + xv.z, 0.f);
        o.w = fmaxf(a * v.w + bb + xv.w, 0.f);
        ((float4*)out)[idx] = o;
    }
}

extern "C" void kernel_launch(void* const* d_in, const int* in_sizes, int n_in,
                              void* d_out, int out_size, void* d_ws, size_t ws_size,
                              hipStream_t stream) {
    const float* x   = (const float*)d_in[0];
    const float* w1  = (const float*)d_in[1];
    const float* g1  = (const float*)d_in[2];
    const float* b1  = (const float*)d_in[3];
    const float* wr  = (const float*)d_in[4];
    const float* gr  = (const float*)d_in[5];
    const float* br  = (const float*)d_in[6];
    const float* wsp = (const float*)d_in[7];
    const float* g2  = (const float*)d_in[8];
    const float* b2  = (const float*)d_in[9];
    const float* w3  = (const float*)d_in[10];
    const float* g3  = (const float*)d_in[11];
    const float* b3  = (const float*)d_in[12];
    float* out = (float*)d_out;
    float* w   = (float*)d_ws;
    float* y1   = w + OFF_Y1;
    float* tr   = w + OFF_TR;
    float* w1t  = w + OFF_WT;
    float* w3t  = w + OFF_WT + 16384;
    float* out2 = w + OFF_OUT2;
    float* y3   = w + OFF_Y3;
    float* st   = w + OFF_ST;

    hipMemsetAsync(st, 0, 2048 * sizeof(float), stream);
    k_wt<<<128, 256, 0, stream>>>(w1, w3, w1t, w3t);
    k_conv1<<<NBLK, 256, 0, stream>>>(x, w1t, y1, st);
    k_fin<<<1, 64, 0, stream>>>(st + ACC1, st + FIN1, g1, b1, 64);
    k_bn1_convr<<<NBLK, 256, 0, stream>>>(y1, wr, tr, st);
    k_fin<<<1, 64, 0, stream>>>(st + ACCR, st + FINR, gr, br, 16);
    k_invol<<<448, 256, 0, stream>>>(y1, tr, wsp, out2, st);
    k_fin<<<1, 64, 0, stream>>>(st + ACC2, st + FIN2, g2, b2, 64);
    k_bn2_conv3<<<NBLK * 4, 256, 0, stream>>>(out2, w3t, y3, st);
    k_fin<<<1, 256, 0, stream>>>(st + ACC3, st + FIN3, g3, b3, 256);
    k_final<<<6272, 256, 0, stream>>>(y3, x, out, st);
}

// Round 6
// 293.320 us; speedup vs baseline: 2.4824x; 1.0092x over previous
//
#include <hip/hip_runtime.h>

#define HW 3136          // 56*56
#define NPIX 25088       // 8*3136
#define NBLK 392         // NPIX/64

// workspace float offsets
#define OFF_Y1   0u
#define OFF_TR   1605632u
#define OFF_WT   2007040u      // w1t (16384) + w3t (16384)
#define OFF_OUT2 6924288u
#define OFF_Y3   8529920u
#define OFF_ST   14952448u
// stats sub-offsets (floats, relative to st base). acc: [C]=sum, [C..2C)=sumsq
#define ACC1 0
#define ACCR 128
#define ACC2 160
#define ACC3 288
#define FIN1 800
#define FINR 928
#define FIN2 960
#define FIN3 1088

__device__ __forceinline__ float wave_sum(float v) {
    #pragma unroll
    for (int off = 32; off > 0; off >>= 1) v += __shfl_xor(v, off, 64);
    return v;
}

// ---- K0: transpose weights w1[64][256]->w1t[256][64], w3[256][64]->w3t[64][256]
__global__ __launch_bounds__(256) void k_wt(const float* __restrict__ w1,
        const float* __restrict__ w3, float* __restrict__ w1t, float* __restrict__ w3t) {
    int i = blockIdx.x * 256 + threadIdx.x;
    if (i < 16384) {
        int oc = i >> 8, ic = i & 255;
        w1t[ic * 64 + oc] = w1[i];
    } else {
        int j = i - 16384;
        int oc = j >> 6, ic = j & 63;
        w3t[ic * 256 + oc] = w3[j];
    }
}

// ---- K1: conv1x1 256->64 + stats -------------------------------------------
// Barrier-free main loop: weight panel (256x32) in LDS, x streamed from global.
// grid = NBLK*2 (pix-tile x oc-half); thread = 4 pix x 2 oc.
__global__ __launch_bounds__(256, 2) void k_conv1(const float* __restrict__ x,
        const float* __restrict__ w1t, float* __restrict__ y1, float* __restrict__ st) {
    __shared__ float ws[256][32];   // [ic][oc-half]
    int t = threadIdx.x, blk = blockIdx.x;
    int oh = blk & 1, pb = blk >> 1;
    int b = pb / 49, hw0 = (pb % 49) * 64;
    int tx = t & 15, ty = t >> 4;   // pix group (4 pix) / oc pair
    #pragma unroll
    for (int i = 0; i < 8; i++) {
        int e = i * 256 + t;
        int ic = e >> 3, c4 = e & 7;
        *(float4*)&ws[ic][c4 * 4] = *(const float4*)&w1t[ic * 64 + oh * 32 + c4 * 4];
    }
    __syncthreads();
    float a00 = 0.f, a01 = 0.f, a02 = 0.f, a03 = 0.f;
    float a10 = 0.f, a11 = 0.f, a12 = 0.f, a13 = 0.f;
    const float* xp = x + (size_t)b * 256 * HW + hw0 + tx * 4;
    #pragma unroll 8
    for (int ic = 0; ic < 256; ic++) {
        float4 xv = *(const float4*)(xp + (size_t)ic * HW);
        float2 wv = *(const float2*)&ws[ic][ty * 2];
        a00 = fmaf(wv.x, xv.x, a00); a01 = fmaf(wv.x, xv.y, a01);
        a02 = fmaf(wv.x, xv.z, a02); a03 = fmaf(wv.x, xv.w, a03);
        a10 = fmaf(wv.y, xv.x, a10); a11 = fmaf(wv.y, xv.y, a11);
        a12 = fmaf(wv.y, xv.z, a12); a13 = fmaf(wv.y, xv.w, a13);
    }
    #pragma unroll
    for (int io = 0; io < 2; io++) {
        int oc = oh * 32 + ty * 2 + io;
        float4 o = io ? make_float4(a10, a11, a12, a13) : make_float4(a00, a01, a02, a03);
        *(float4*)&y1[((b * 64) + oc) * HW + hw0 + tx * 4] = o;
        float s = o.x + o.y + o.z + o.w;
        float q = o.x * o.x + o.y * o.y + o.z * o.z + o.w * o.w;
        #pragma unroll
        for (int off = 1; off <= 8; off <<= 1) {
            s += __shfl_xor(s, off, 64);
            q += __shfl_xor(q, off, 64);
        }
        if (tx == 0) {
            atomicAdd(&st[ACC1 + oc], s);
            atomicAdd(&st[ACC1 + 64 + oc], q);
        }
    }
}

// ---- finalize BN stats -> per-channel affine (a,b) -------------------------
__global__ void k_fin(const float* __restrict__ acc, float* __restrict__ fin,
                      const float* __restrict__ gamma, const float* __restrict__ beta, int C) {
    int c = threadIdx.x;
    if (c < C) {
        float mean = acc[c] * (1.0f / (float)NPIX);
        float var  = acc[C + c] * (1.0f / (float)NPIX) - mean * mean;
        float rstd = rsqrtf(var + 1e-5f);
        float a = gamma[c] * rstd;
        fin[c] = a;
        fin[C + c] = beta[c] - mean * a;
    }
}

// ---- K3: apply BN1+ReLU in-place, conv 64->16 + stats ----------------------
__global__ __launch_bounds__(256, 4) void k_bn1_convr(float* __restrict__ y1,
        const float* __restrict__ wr, float* __restrict__ tr, float* __restrict__ st) {
    __shared__ float ys[64][64];    // [ic][pix], BN1+ReLU applied
    __shared__ float wsh[16][64];   // [oc][ic]
    int t = threadIdx.x, pb = blockIdx.x;
    int b = pb / 49, hw0 = (pb % 49) * 64;
    int tx = t & 15, ty = t >> 4;   // pix group (4 pix) / oc (one of 16)
    #pragma unroll
    for (int i = 0; i < 16; i++) {
        int e = i * 256 + t, c = e >> 6, p = e & 63;
        int gi = ((b * 64) + c) * HW + hw0 + p;
        float v = y1[gi];
        v = fmaxf(st[FIN1 + c] * v + st[FIN1 + 64 + c], 0.f);
        ys[c][p] = v;
        y1[gi] = v;                 // y1 becomes y1r
    }
    #pragma unroll
    for (int i = 0; i < 4; i++) {
        int e = i * 256 + t;
        wsh[e >> 6][e & 63] = wr[e];
    }
    __syncthreads();
    float a0 = 0.f, a1 = 0.f, a2 = 0.f, a3 = 0.f;
    #pragma unroll 8
    for (int c = 0; c < 64; c++) {
        float4 yv = *(const float4*)&ys[c][tx * 4];
        float wv = wsh[ty][c];
        a0 = fmaf(wv, yv.x, a0); a1 = fmaf(wv, yv.y, a1);
        a2 = fmaf(wv, yv.z, a2); a3 = fmaf(wv, yv.w, a3);
    }
    *(float4*)&tr[((b * 16) + ty) * HW + hw0 + tx * 4] = make_float4(a0, a1, a2, a3);
    float s = a0 + a1 + a2 + a3;
    float q = a0 * a0 + a1 * a1 + a2 * a2 + a3 * a3;
    #pragma unroll
    for (int off = 1; off <= 8; off <<= 1) {
        s += __shfl_xor(s, off, 64);
        q += __shfl_xor(q, off, 64);
    }
    if (tx == 0) {
        atomicAdd(&st[ACCR + ty], s);
        atomicAdd(&st[ACCR + 16 + ty], q);
    }
}

// ---- K6: fused BNr+ReLU -> span conv (kernels in regs) -> involution + stats
// Split: each block handles 8 of the group's 16 channels (grid x2, LDS ~39KB).
__global__ __launch_bounds__(256) void k_invol(const float* __restrict__ y1r,
        const float* __restrict__ tr, const float* __restrict__ wsp,
        float* __restrict__ out2, float* __restrict__ st) {
    __shared__ float ts[16][256];      // BNr+ReLU'd tr tile (224 used)
    __shared__ float sw[49][16];       // span weights for this group
    __shared__ float ps[8][10][64];    // y1r halo tile (8 channels)
    __shared__ float red[4][16];
    int t = threadIdx.x, bidx = blockIdx.x;     // (((b*4+g)*14 + ht)*2 + h)
    int h = bidx & 1, r2 = bidx >> 1;
    int ht = r2 % 14;
    int bg = r2 / 14;
    int g = bg & 3, b = bg >> 2;
    int h0 = ht * 4;
    int c0 = h * 8;                    // channel offset within group
    // stage ts (BNr+ReLU applied) — all 16 channels (needed for kernel gen)
    #pragma unroll
    for (int i = 0; i < 16; i++) {
        int e = i * 256 + t, c = e >> 8, p = e & 255;
        if (p < 224) {
            float v = tr[((b * 16) + c) * HW + h0 * 56 + p];
            ts[c][p] = fmaxf(st[FINR + c] * v + st[FINR + 16 + c], 0.f);
        }
    }
    // stage span weights (group g): contiguous 784 floats
    for (int e = t; e < 784; e += 256) sw[e >> 4][e & 15] = wsp[g * 784 + e];
    // stage y1r halo for this block's 8 channels
    for (int i = 0; i < 20; i++) {
        int e = i * 256 + t;
        int c = e / 640, rem = e - c * 640;
        int r = rem >> 6, wc = rem & 63;
        int gh = h0 + r - 3, gw = wc - 3;
        float v = 0.f;
        if (gh >= 0 && gh < 56 && gw >= 0 && gw < 56)
            v = y1r[((b * 64) + g * 16 + c0 + c) * HW + gh * 56 + gw];
        ps[c][r][wc] = v;
    }
    __syncthreads();
    float accv[8];
    #pragma unroll
    for (int c = 0; c < 8; c++) accv[c] = 0.f;
    bool active = t < 224;
    if (active) {
        int lh = t / 56, lw = t % 56;
        // per-pixel kernel generation into registers (uses all 16 channels)
        float tsr[16];
        #pragma unroll
        for (int c = 0; c < 16; c++) tsr[c] = ts[c][t];
        float kr[49];
        #pragma unroll
        for (int k = 0; k < 49; k++) {
            const float4* swr = (const float4*)&sw[k][0];
            float4 u0 = swr[0], u1 = swr[1], u2 = swr[2], u3 = swr[3];
            float v = u0.x * tsr[0];
            v = fmaf(u0.y, tsr[1], v);  v = fmaf(u0.z, tsr[2], v);  v = fmaf(u0.w, tsr[3], v);
            v = fmaf(u1.x, tsr[4], v);  v = fmaf(u1.y, tsr[5], v);  v = fmaf(u1.z, tsr[6], v);
            v = fmaf(u1.w, tsr[7], v);  v = fmaf(u2.x, tsr[8], v);  v = fmaf(u2.y, tsr[9], v);
            v = fmaf(u2.z, tsr[10], v); v = fmaf(u2.w, tsr[11], v); v = fmaf(u3.x, tsr[12], v);
            v = fmaf(u3.y, tsr[13], v); v = fmaf(u3.z, tsr[14], v); v = fmaf(u3.w, tsr[15], v);
            kr[k] = v;
        }
        // involution MAC over this block's 8 channels
        #pragma unroll
        for (int k = 0; k < 49; k++) {
            int ki = k / 7, kj = k % 7;
            float kv = kr[k];
            #pragma unroll
            for (int c = 0; c < 8; c++)
                accv[c] = fmaf(kv, ps[c][lh + ki][lw + kj], accv[c]);
        }
        int hw = h0 * 56 + t;
        #pragma unroll
        for (int c = 0; c < 8; c++)
            out2[((b * 64) + g * 16 + c0 + c) * HW + hw] = accv[c];
    }
    int wave = t >> 6, lane = t & 63;
    #pragma unroll
    for (int c = 0; c < 8; c++) {
        float v = active ? accv[c] : 0.f;
        float s  = wave_sum(v);
        float s2 = wave_sum(v * v);
        if (lane == 0) { red[wave][c] = s; red[wave][8 + c] = s2; }
    }
    __syncthreads();
    if (t < 16) {
        float s = red[0][t] + red[1][t] + red[2][t] + red[3][t];
        int c = t & 7, isq = t >> 3;
        atomicAdd(&st[ACC2 + isq * 64 + g * 16 + c0 + c], s);
    }
}

// ---- K7: apply BN2+ReLU, conv 64->256 + stats ------------------------------
// occ chunk on grid (blockIdx & 3): one staging + one inner loop per block.
__global__ __launch_bounds__(256, 4) void k_bn2_conv3(const float* __restrict__ out2,
        const float* __restrict__ w3t, float* __restrict__ y3, float* __restrict__ st) {
    __shared__ float os[64][64];    // [ic][pix], BN2+ReLU applied
    __shared__ float wst[64][64];   // [ic][oc-chunk]
    int t = threadIdx.x, blk = blockIdx.x;
    int occ = blk & 3, pb = blk >> 2;
    int b = pb / 49, hw0 = (pb % 49) * 64;
    int tx = t & 15, ty = t >> 4;
    #pragma unroll
    for (int i = 0; i < 16; i++) {
        int e = i * 256 + t, c = e >> 6, p = e & 63;
        float v = out2[((b * 64) + c) * HW + hw0 + p];
        os[c][p] = fmaxf(st[FIN2 + c] * v + st[FIN2 + 64 + c], 0.f);
        wst[c][p] = w3t[c * 256 + occ * 64 + p];
    }
    __syncthreads();
    float acc[4][4];
    #pragma unroll
    for (int i = 0; i < 4; i++)
        #pragma unroll
        for (int j = 0; j < 4; j++) acc[i][j] = 0.f;
    #pragma unroll 8
    for (int c = 0; c < 64; c++) {
        float4 xv = *(const float4*)&os[c][tx * 4];
        float4 wv = *(const float4*)&wst[c][ty * 4];
        float xa[4] = {xv.x, xv.y, xv.z, xv.w};
        float wa[4] = {wv.x, wv.y, wv.z, wv.w};
        #pragma unroll
        for (int i = 0; i < 4; i++)
            #pragma unroll
            for (int j = 0; j < 4; j++) acc[i][j] = fmaf(wa[i], xa[j], acc[i][j]);
    }
    #pragma unroll
    for (int i = 0; i < 4; i++) {
        int oc = occ * 64 + ty * 4 + i;
        float4 o = make_float4(acc[i][0], acc[i][1], acc[i][2], acc[i][3]);
        *(float4*)&y3[((b * 256) + oc) * HW + hw0 + tx * 4] = o;
        float s = o.x + o.y + o.z + o.w;
        float q = o.x * o.x + o.y * o.y + o.z * o.z + o.w * o.w;
        #pragma unroll
        for (int off = 1; off <= 8; off <<= 1) {
            s += __shfl_xor(s, off, 64);
            q += __shfl_xor(q, off, 64);
        }
        if (tx == 0) {
            atomicAdd(&st[ACC3 + oc], s);
            atomicAdd(&st[ACC3 + 256 + oc], q);
        }
    }
}

// ---- K9: BN3 + residual + ReLU (float4) ------------------------------------
__global__ __launch_bounds__(256) void k_final(const float* __restrict__ y3,
        const float* __restrict__ x, float* __restrict__ out, const float* __restrict__ st) {
    int idx = blockIdx.x * 256 + threadIdx.x;   // float4 index
    if (idx < 1605632) {
        int c = (idx / 784) & 255;
        float a = st[FIN3 + c], bb = st[FIN3 + 256 + c];
        float4 v  = ((const float4*)y3)[idx];
        float4 xv = ((const float4*)x)[idx];
        float4 o;
        o.x = fmaxf(a * v.x + bb + xv.x, 0.f);
        o.y = fmaxf(a * v.y + bb + xv.y, 0.f);
        o.z = fmaxf(a * v.z + bb + xv.z, 0.f);
        o.w = fmaxf(a * v.w + bb + xv.w, 0.f);
        ((float4*)out)[idx] = o;
    }
}

extern "C" void kernel_launch(void* const* d_in, const int* in_sizes, int n_in,
                              void* d_out, int out_size, void* d_ws, size_t ws_size,
                              hipStream_t stream) {
    const float* x   = (const float*)d_in[0];
    const float* w1  = (const float*)d_in[1];
    const float* g1  = (const float*)d_in[2];
    const float* b1  = (const float*)d_in[3];
    const float* wr  = (const float*)d_in[4];
    const float* gr  = (const float*)d_in[5];
    const float* br  = (const float*)d_in[6];
    const float* wsp = (const float*)d_in[7];
    const float* g2  = (const float*)d_in[8];
    const float* b2  = (const float*)d_in[9];
    const float* w3  = (const float*)d_in[10];
    const float* g3  = (const float*)d_in[11];
    const float* b3  = (const float*)d_in[12];
    float* out = (float*)d_out;
    float* w   = (float*)d_ws;
    float* y1   = w + OFF_Y1;
    float* tr   = w + OFF_TR;
    float* w1t  = w + OFF_WT;
    float* w3t  = w + OFF_WT + 16384;
    float* out2 = w + OFF_OUT2;
    float* y3   = w + OFF_Y3;
    float* st   = w + OFF_ST;

    hipMemsetAsync(st, 0, 2048 * sizeof(float), stream);
    k_wt<<<128, 256, 0, stream>>>(w1, w3, w1t, w3t);
    k_conv1<<<NBLK * 2, 256, 0, stream>>>(x, w1t, y1, st);
    k_fin<<<1, 64, 0, stream>>>(st + ACC1, st + FIN1, g1, b1, 64);
    k_bn1_convr<<<NBLK, 256, 0, stream>>>(y1, wr, tr, st);
    k_fin<<<1, 64, 0, stream>>>(st + ACCR, st + FINR, gr, br, 16);
    k_invol<<<896, 256, 0, stream>>>(y1, tr, wsp, out2, st);
    k_fin<<<1, 64, 0, stream>>>(st + ACC2, st + FIN2, g2, b2, 64);
    k_bn2_conv3<<<NBLK * 4, 256, 0, stream>>>(out2, w3t, y3, st);
    k_fin<<<1, 256, 0, stream>>>(st + ACC3, st + FIN3, g3, b3, 256);
    k_final<<<6272, 256, 0, stream>>>(y3, x, out, st);
}